// Round 1
// baseline (281.145 us; speedup 1.0000x reference)
//
#include <hip/hip_runtime.h>
#include <math.h>

#define NB 64
#define NA 5
#define NC 80
#define HH 38
#define WW 38
#define HW (HH*WW)          // 1444
#define CELLS (NA*HW)       // 7220
#define NT 50
#define NCH 85

__constant__ float c_aw[NA] = {0.57273f, 1.87446f, 3.33843f, 7.88282f, 9.77052f};
__constant__ float c_ah[NA] = {0.677385f, 2.06253f, 5.47434f, 3.52778f, 9.16828f};

__global__ __launch_bounds__(256) void yolo_main(const float* __restrict__ pred,
                                                 const float* __restrict__ tgt,
                                                 float* __restrict__ accum) {
    const int b = blockIdx.y;
    __shared__ float s_gx[NT], s_gy[NT], s_gw[NT], s_gh[NT];
    __shared__ float s_tx[NT], s_ty[NT], s_tw[NT], s_th[NT];
    __shared__ int s_cell[NT], s_cls[NT];
    __shared__ int s_vc;
    __shared__ float s_red[4*3];

    const int tid = threadIdx.x;

    // valid prefix count (cumprod semantics: stop at first cx == -1)
    if (tid == 0) {
        const float* tb = tgt + (size_t)b*NT*5;
        int vc = 0;
        for (; vc < NT; ++vc) if (tb[vc*5 + 1] == -1.0f) break;
        s_vc = vc;
    }
    __syncthreads();
    const int vc = s_vc;

    // per-target derived values into LDS
    if (tid < vc) {
        const float* tr = tgt + ((size_t)b*NT + tid)*5;
        float cls = tr[0], cx = tr[1], cy = tr[2], wn = tr[3], hn = tr[4];
        float gx = cx * WW, gy = cy * HH, gw = wn * WW, gh = hn * HH;
        int best = 0; float bi = -1.0f;
        #pragma unroll
        for (int a = 0; a < NA; ++a) {
            float inter = fminf(gw, c_aw[a]) * fminf(gh, c_ah[a]);
            float un = gw*gh + c_aw[a]*c_ah[a] - inter;
            float iou = (un > 0.f) ? inter/un : 0.f;
            if (iou > bi) { bi = iou; best = a; }   // first-max like jnp.argmax
        }
        int gi = (int)gx; gi = gi < 0 ? 0 : (gi > WW-1 ? WW-1 : gi);
        int gj = (int)gy; gj = gj < 0 ? 0 : (gj > HH-1 ? HH-1 : gj);
        s_gx[tid] = gx; s_gy[tid] = gy; s_gw[tid] = gw; s_gh[tid] = gh;
        s_tx[tid] = gx - (float)gi; s_ty[tid] = gy - (float)gj;
        s_tw[tid] = logf(gw / c_aw[best]);
        s_th[tid] = logf(gh / c_ah[best]);
        s_cell[tid] = (best*HH + gj)*WW + gi;
        s_cls[tid] = (int)cls;
    }
    __syncthreads();

    float l_main = 0.f, l_cls = 0.f, l_n = 0.f;
    const int cell = blockIdx.x * 256 + tid;
    if (cell < CELLS) {
        const int a   = cell / HW;
        const int rem = cell - a*HW;
        const int j   = rem / WW;
        const int i   = rem - j*WW;
        const float* base = pred + ((size_t)(b*(NA*NCH) + a*NCH))*HW + rem;
        float p0 = base[0];
        float p1 = base[HW];
        float p2 = base[2*HW];
        float p3 = base[3*HW];
        float p4 = base[4*HW];
        float x    = 1.f/(1.f + expf(-p0));
        float y    = 1.f/(1.f + expf(-p1));
        float conf = 1.f/(1.f + expf(-p4));
        float bx = x + (float)i;
        float by = y + (float)j;
        float bw = expf(p2) * c_aw[a];
        float bh = expf(p3) * c_ah[a];
        float hbw = bw*0.5f, hbh = bh*0.5f;
        float pa = bw*bh;

        float maxiou = 0.f, miou = 0.f;
        int match = -1;
        for (int t = 0; t < vc; ++t) {
            float gx = s_gx[t], gy = s_gy[t], gw = s_gw[t], gh = s_gh[t];
            float mx = fminf(bx - hbw, gx - gw*0.5f);
            float Mx = fmaxf(bx + hbw, gx + gw*0.5f);
            float my = fminf(by - hbh, gy - gh*0.5f);
            float My = fmaxf(by + hbh, gy + gh*0.5f);
            float cw  = bw + gw - (Mx - mx);
            float chh = bh + gh - (My - my);
            float inter = (cw > 0.f && chh > 0.f) ? cw*chh : 0.f;
            float un = pa + gw*gh - inter;
            float iou = (un > 0.f) ? inter/un : 0.f;
            maxiou = fmaxf(maxiou, iou);
            if (s_cell[t] == cell) { match = t; miou = iou; }  // last t wins
        }

        if (match >= 0) {
            float dx = x  - s_tx[match];
            float dy = y  - s_ty[match];
            float dw = p2 - s_tw[match];
            float dh = p3 - s_th[match];
            l_main += dx*dx + dy*dy + dw*dw + dh*dh;   // COORD_SCALE = 1
            float dc = conf - miou;                     // tconf = IoU(gt, own box)
            l_main += 5.0f * dc*dc;                     // OBJ_SCALE = 5
            // class cross-entropy: online logsumexp over 80 logits
            const float* cb = base + (size_t)5*HW;
            const int tc = s_cls[match];
            float m0 = -INFINITY, s0 = 0.f, tl = 0.f;
            for (int c = 0; c < NC; ++c) {
                float v = cb[(size_t)c*HW];
                if (c == tc) tl = v;
                if (v > m0) { s0 = s0*expf(m0 - v) + 1.f; m0 = v; }
                else        { s0 += expf(v - m0); }
            }
            l_cls += (m0 + logf(s0)) - tl;              // -log_softmax[tc]
            l_n += 1.f;
        } else if (maxiou <= 0.6f) {
            l_main += conf*conf;                        // NOOBJ_SCALE = 1, tconf=0
        }
    }

    // block reduction: wave shuffle (64 lanes) then LDS across 4 waves
    #pragma unroll
    for (int off = 32; off > 0; off >>= 1) {
        l_main += __shfl_down(l_main, off, 64);
        l_cls  += __shfl_down(l_cls,  off, 64);
        l_n    += __shfl_down(l_n,    off, 64);
    }
    const int wave = tid >> 6;
    if ((tid & 63) == 0) {
        s_red[wave*3+0] = l_main;
        s_red[wave*3+1] = l_cls;
        s_red[wave*3+2] = l_n;
    }
    __syncthreads();
    if (tid == 0) {
        float a0 = 0.f, a1 = 0.f, a2 = 0.f;
        #pragma unroll
        for (int wv = 0; wv < 4; ++wv) {
            a0 += s_red[wv*3+0]; a1 += s_red[wv*3+1]; a2 += s_red[wv*3+2];
        }
        atomicAdd(&accum[0], a0);
        atomicAdd(&accum[1], a1);
        atomicAdd(&accum[2], a2);
    }
}

__global__ void zero_k(float* w) {
    if (threadIdx.x < 3) w[threadIdx.x] = 0.f;
}

__global__ void fin_k(const float* __restrict__ w, float* __restrict__ out) {
    out[0] = w[0] + w[1] / fmaxf(w[2], 1.0f);
}

extern "C" void kernel_launch(void* const* d_in, const int* in_sizes, int n_in,
                              void* d_out, int out_size, void* d_ws, size_t ws_size,
                              hipStream_t stream) {
    const float* pred = (const float*)d_in[0];
    const float* tgt  = (const float*)d_in[1];
    float* accum = (float*)d_ws;
    float* out   = (float*)d_out;

    hipLaunchKernelGGL(zero_k, dim3(1), dim3(64), 0, stream, accum);
    dim3 grid((CELLS + 255)/256, NB);
    hipLaunchKernelGGL(yolo_main, grid, dim3(256), 0, stream, pred, tgt, accum);
    hipLaunchKernelGGL(fin_k, dim3(1), dim3(1), 0, stream, accum, out);
}

// Round 2
// 227.315 us; speedup vs baseline: 1.2368x; 1.2368x over previous
//
#include <hip/hip_runtime.h>
#include <math.h>

#define NB 64
#define NA 5
#define NC 80
#define HH 38
#define WW 38
#define HW (HH*WW)          // 1444
#define CELLS (NA*HW)       // 7220
#define NT 50
#define NCH 85

// ---- workspace layout (float element offsets) ----
#define TABSZ    (NB*NT)                    // 3200
#define WS_ACCUM 0                          // [2] floats: main-loss sum, cls sum
#define WS_NOBJ  4                          // [NB] floats: per-batch unique-obj count
#define WS_TAB   128                        // 8 float arrays [TABSZ]: gx,gy,gw,gh,tx,ty,tw,th
#define WS_CELL  (WS_TAB + 8*TABSZ)         // int [TABSZ]
#define WS_ACT   (WS_CELL + TABSZ)          // int [TABSZ]
#define WS_VC    (WS_ACT + TABSZ)           // int [NB]
#define WS_CLS   (WS_VC + NB)               // int [TABSZ]

__constant__ float c_aw[NA] = {0.57273f, 1.87446f, 3.33843f, 7.88282f, 9.77052f};
__constant__ float c_ah[NA] = {0.677385f, 2.06253f, 5.47434f, 3.52778f, 9.16828f};

// ---------------- prep: one block (1 wave) per batch ----------------
__global__ __launch_bounds__(64) void prep(const float* __restrict__ tgt,
                                           float* __restrict__ ws) {
    const int b = blockIdx.x;
    const int t = threadIdx.x;
    int* wi = (int*)ws;

    float cls = 0.f, cx = -1.f, cy = 0.f, wn = 0.f, hn = 0.f;
    if (t < NT) {
        const float* tr = tgt + ((size_t)b*NT + t)*5;
        cls = tr[0]; cx = tr[1]; cy = tr[2]; wn = tr[3]; hn = tr[4];
    }
    // valid prefix: first t with cx == -1 terminates (lanes >= NT read as -1)
    unsigned long long inv = __ballot(cx == -1.0f);
    const int vc = (int)__ffsll((unsigned long long)inv) - 1;   // NT<64 => inv != 0

    __shared__ int s_cell[NT];
    int cell = -1;
    float gx = cx*WW, gy = cy*HH, gw = wn*WW, gh = hn*HH;
    float twv = 0.f, thv = 0.f, txv = 0.f, tyv = 0.f;
    if (t < vc) {
        int best = 0; float bi = -1.0f;
        #pragma unroll
        for (int a = 0; a < NA; ++a) {
            float inter = fminf(gw, c_aw[a]) * fminf(gh, c_ah[a]);
            float un = gw*gh + c_aw[a]*c_ah[a] - inter;
            float iou = (un > 0.f) ? inter/un : 0.f;
            if (iou > bi) { bi = iou; best = a; }   // first-max == jnp.argmax
        }
        int gi = (int)gx; gi = gi < 0 ? 0 : (gi > WW-1 ? WW-1 : gi);
        int gj = (int)gy; gj = gj < 0 ? 0 : (gj > HH-1 ? HH-1 : gj);
        txv = gx - (float)gi; tyv = gy - (float)gj;
        twv = logf(gw / c_aw[best]);
        thv = logf(gh / c_ah[best]);
        cell = (best*HH + gj)*WW + gi;
        s_cell[t] = cell;
    }
    __syncthreads();

    int active = 0;
    if (t < vc) {
        active = 1;
        for (int u = t+1; u < vc; ++u)
            if (s_cell[u] == cell) { active = 0; break; }   // last-t-wins dedup
        const int o = b*NT + t;
        ws[WS_TAB + 0*TABSZ + o] = gx;
        ws[WS_TAB + 1*TABSZ + o] = gy;
        ws[WS_TAB + 2*TABSZ + o] = gw;
        ws[WS_TAB + 3*TABSZ + o] = gh;
        ws[WS_TAB + 4*TABSZ + o] = txv;
        ws[WS_TAB + 5*TABSZ + o] = tyv;
        ws[WS_TAB + 6*TABSZ + o] = twv;
        ws[WS_TAB + 7*TABSZ + o] = thv;
        wi[WS_CELL + o] = cell;
        wi[WS_ACT  + o] = active;
        wi[WS_CLS  + o] = (int)cls;
    }
    unsigned long long am = __ballot(active != 0);
    if (t == 0) {
        ws[WS_NOBJ + b] = (float)__popcll(am);   // unique obj cells this batch
        wi[WS_VC + b] = vc;
        if (b == 0) { ws[WS_ACCUM+0] = 0.f; ws[WS_ACCUM+1] = 0.f; }
    }
}

// ---------------- main: conf + coord + noobj, uniform waves ----------------
__global__ __launch_bounds__(256) void yolo_main(const float* __restrict__ pred,
                                                 float* __restrict__ ws) {
    const int b = blockIdx.y;
    const int tid = threadIdx.x;
    const int* wi = (const int*)ws;

    __shared__ float s_gx[NT], s_gy[NT], s_gw[NT], s_gh[NT];
    __shared__ float s_tx[NT], s_ty[NT], s_tw[NT], s_th[NT];
    __shared__ int s_cell[NT];
    __shared__ float s_red[4];

    const int vc = wi[WS_VC + b];
    if (tid < vc) {
        const int o = b*NT + tid;
        s_gx[tid] = ws[WS_TAB + 0*TABSZ + o];
        s_gy[tid] = ws[WS_TAB + 1*TABSZ + o];
        s_gw[tid] = ws[WS_TAB + 2*TABSZ + o];
        s_gh[tid] = ws[WS_TAB + 3*TABSZ + o];
        s_tx[tid] = ws[WS_TAB + 4*TABSZ + o];
        s_ty[tid] = ws[WS_TAB + 5*TABSZ + o];
        s_tw[tid] = ws[WS_TAB + 6*TABSZ + o];
        s_th[tid] = ws[WS_TAB + 7*TABSZ + o];
        s_cell[tid] = wi[WS_CELL + o];
    }
    __syncthreads();

    float l = 0.f;
    const int cell = blockIdx.x * 256 + tid;
    if (cell < CELLS) {
        const int a   = cell / HW;
        const int rem = cell - a*HW;
        const int j   = rem / WW;
        const int i   = rem - j*WW;
        const float* base = pred + ((size_t)(b*(NA*NCH) + a*NCH))*HW + rem;
        float p0 = base[0];
        float p1 = base[HW];
        float p2 = base[2*HW];
        float p3 = base[3*HW];
        float p4 = base[4*HW];
        float x    = 1.f/(1.f + expf(-p0));
        float y    = 1.f/(1.f + expf(-p1));
        float conf = 1.f/(1.f + expf(-p4));
        float bx = x + (float)i;
        float by = y + (float)j;
        float bw = expf(p2) * c_aw[a];
        float bh = expf(p3) * c_ah[a];
        float hbw = bw*0.5f, hbh = bh*0.5f;
        float pa = bw*bh;

        float maxiou = 0.f, miou = 0.f;
        int match = -1;
        for (int t = 0; t < vc; ++t) {
            float gx = s_gx[t], gy = s_gy[t], gw = s_gw[t], gh = s_gh[t];
            float mx = fminf(bx - hbw, gx - gw*0.5f);
            float Mx = fmaxf(bx + hbw, gx + gw*0.5f);
            float my = fminf(by - hbh, gy - gh*0.5f);
            float My = fmaxf(by + hbh, gy + gh*0.5f);
            float cw  = bw + gw - (Mx - mx);
            float chh = bh + gh - (My - my);
            float inter = (cw > 0.f && chh > 0.f) ? cw*chh : 0.f;
            float un = pa + gw*gh - inter;
            float iou = (un > 0.f) ? inter/un : 0.f;
            maxiou = fmaxf(maxiou, iou);
            if (s_cell[t] == cell) { match = t; miou = iou; }  // last t wins
        }

        if (match >= 0) {
            float dx = x  - s_tx[match];
            float dy = y  - s_ty[match];
            float dw = p2 - s_tw[match];
            float dh = p3 - s_th[match];
            l += dx*dx + dy*dy + dw*dw + dh*dh;      // COORD_SCALE = 1
            float dc = conf - miou;
            l += 5.0f * dc*dc;                        // OBJ_SCALE = 5
        } else if (maxiou <= 0.6f) {
            l += conf*conf;                           // NOOBJ_SCALE = 1
        }
    }

    #pragma unroll
    for (int off = 32; off > 0; off >>= 1) l += __shfl_down(l, off, 64);
    if ((tid & 63) == 0) s_red[tid >> 6] = l;
    __syncthreads();
    if (tid == 0)
        atomicAdd(&ws[WS_ACCUM+0], s_red[0]+s_red[1]+s_red[2]+s_red[3]);
}

// ---------------- clsk: one wave per target; 80 logits parallel across lanes ----------------
__global__ __launch_bounds__(256) void clsk(const float* __restrict__ pred,
                                            float* __restrict__ ws) {
    const int w = blockIdx.x*4 + (threadIdx.x >> 6);
    const int lane = threadIdx.x & 63;
    const int b = w / NT, t = w - b*NT;
    const int* wi = (const int*)ws;

    if (t >= wi[WS_VC + b] || !wi[WS_ACT + b*NT + t]) return;

    const int cell = wi[WS_CELL + b*NT + t];
    const int a = cell / HW, rem = cell - a*HW;
    const float* logit = pred + ((size_t)(b*(NA*NCH) + a*NCH) + 5)*HW + rem;

    float v0 = logit[(size_t)lane*HW];                                   // c = lane
    float v1 = (lane < NC-64) ? logit[(size_t)(lane+64)*HW] : -INFINITY; // c = lane+64

    float m = fmaxf(v0, v1);
    #pragma unroll
    for (int off = 32; off > 0; off >>= 1) m = fmaxf(m, __shfl_xor(m, off, 64));

    const int tc = wi[WS_CLS + b*NT + t];
    float s  = expf(v0 - m) + ((lane < NC-64) ? expf(v1 - m) : 0.f);
    float tl = ((lane == tc) ? v0 : 0.f) + ((lane + 64 == tc) ? v1 : 0.f);
    #pragma unroll
    for (int off = 32; off > 0; off >>= 1) {
        s  += __shfl_xor(s,  off, 64);
        tl += __shfl_xor(tl, off, 64);
    }
    if (lane == 0) atomicAdd(&ws[WS_ACCUM+1], (m + logf(s)) - tl);
}

// ---------------- finalize ----------------
__global__ __launch_bounds__(64) void fin_k(const float* __restrict__ ws,
                                            float* __restrict__ out) {
    float n = ws[WS_NOBJ + threadIdx.x];   // NB == 64 lanes
    #pragma unroll
    for (int off = 32; off > 0; off >>= 1) n += __shfl_down(n, off, 64);
    if (threadIdx.x == 0)
        out[0] = ws[WS_ACCUM+0] + ws[WS_ACCUM+1] / fmaxf(n, 1.0f);
}

extern "C" void kernel_launch(void* const* d_in, const int* in_sizes, int n_in,
                              void* d_out, int out_size, void* d_ws, size_t ws_size,
                              hipStream_t stream) {
    const float* pred = (const float*)d_in[0];
    const float* tgt  = (const float*)d_in[1];
    float* ws  = (float*)d_ws;
    float* out = (float*)d_out;

    hipLaunchKernelGGL(prep, dim3(NB), dim3(64), 0, stream, tgt, ws);
    hipLaunchKernelGGL(yolo_main, dim3((CELLS+255)/256, NB), dim3(256), 0, stream, pred, ws);
    hipLaunchKernelGGL(clsk, dim3(NB*NT/4), dim3(256), 0, stream, pred, ws);
    hipLaunchKernelGGL(fin_k, dim3(1), dim3(64), 0, stream, ws, out);
}

// Round 3
// 199.369 us; speedup vs baseline: 1.4102x; 1.1402x over previous
//
#include <hip/hip_runtime.h>
#include <math.h>

#define NB 64
#define NA 5
#define NC 80
#define HH 38
#define WW 38
#define HW (HH*WW)          // 1444
#define CELLS (NA*HW)       // 7220
#define NT 50
#define NCH 85
#define MBLK 29             // main blocks per batch: 29*256 = 7424 >= 7220

// ---- workspace layout (float element offsets); every slot written every launch ----
#define WS_PART 0                    // [NB*MBLK] per-main-block partial of coord+conf loss
#define WS_CLSP (NB*MBLK)            // [NB] per-batch class-loss sum
#define WS_NOBJ (NB*MBLK + NB)       // [NB] per-batch unique-obj count

__constant__ float c_aw[NA] = {0.57273f, 1.87446f, 3.33843f, 7.88282f, 9.77052f};
__constant__ float c_ah[NA] = {0.677385f, 2.06253f, 5.47434f, 3.52778f, 9.16828f};

__global__ __launch_bounds__(256) void yolo_fused(const float* __restrict__ pred,
                                                  const float* __restrict__ tgt,
                                                  float* __restrict__ ws) {
    const int b   = blockIdx.y;
    const int bx  = blockIdx.x;
    const int tid = threadIdx.x;

    __shared__ float s_gx[NT], s_gy[NT], s_gw[NT], s_gh[NT];
    __shared__ float s_tx[NT], s_ty[NT], s_tw[NT], s_th[NT];
    __shared__ int   s_cell[NT], s_cls[NT];
    __shared__ int   s_vc;
    __shared__ float s_red[4];

    // ---- prep: wave 0 derives the target table (parallel across lanes) ----
    if (tid < 64) {
        float cls = 0.f, cx = -1.f, cy = 0.f, wn = 0.f, hn = 0.f;
        if (tid < NT) {
            const float* tr = tgt + ((size_t)b*NT + tid)*5;
            cls = tr[0]; cx = tr[1]; cy = tr[2]; wn = tr[3]; hn = tr[4];
        }
        unsigned long long inv = __ballot(cx == -1.0f);   // lanes >= NT force bits set
        const int vc = (int)__ffsll(inv) - 1;
        if (tid == 0) s_vc = vc;
        if (tid < vc) {
            float gx = cx*WW, gy = cy*HH, gw = wn*WW, gh = hn*HH;
            int best = 0; float bi = -1.0f;
            #pragma unroll
            for (int a = 0; a < NA; ++a) {
                float inter = fminf(gw, c_aw[a]) * fminf(gh, c_ah[a]);
                float un = gw*gh + c_aw[a]*c_ah[a] - inter;
                float iou = (un > 0.f) ? inter/un : 0.f;
                if (iou > bi) { bi = iou; best = a; }      // first-max == jnp.argmax
            }
            int gi = (int)gx; gi = gi < 0 ? 0 : (gi > WW-1 ? WW-1 : gi);
            int gj = (int)gy; gj = gj < 0 ? 0 : (gj > HH-1 ? HH-1 : gj);
            s_gx[tid] = gx; s_gy[tid] = gy; s_gw[tid] = gw; s_gh[tid] = gh;
            s_tx[tid] = gx - (float)gi; s_ty[tid] = gy - (float)gj;
            s_tw[tid] = logf(gw / c_aw[best]);
            s_th[tid] = logf(gh / c_ah[best]);
            s_cell[tid] = (best*HH + gj)*WW + gi;
            s_cls[tid]  = (int)cls;
        }
    }
    __syncthreads();
    const int vc = s_vc;

    if (bx < MBLK) {
        // ---------- main: conf + coord + noobj ----------
        float l = 0.f;
        const int cell = bx * 256 + tid;
        if (cell < CELLS) {
            const int a   = cell / HW;
            const int rem = cell - a*HW;
            const int j   = rem / WW;
            const int i   = rem - j*WW;
            const float* base = pred + ((size_t)(b*(NA*NCH) + a*NCH))*HW + rem;
            float p0 = base[0];
            float p1 = base[HW];
            float p2 = base[2*HW];
            float p3 = base[3*HW];
            float p4 = base[4*HW];
            float x    = 1.f/(1.f + expf(-p0));
            float y    = 1.f/(1.f + expf(-p1));
            float conf = 1.f/(1.f + expf(-p4));
            float bxx = x + (float)i;
            float byy = y + (float)j;
            float bw = expf(p2) * c_aw[a];
            float bh = expf(p3) * c_ah[a];
            float hbw = bw*0.5f, hbh = bh*0.5f;
            float pa = bw*bh;

            float maxiou = 0.f, miou = 0.f;
            int match = -1;
            for (int t = 0; t < vc; ++t) {
                float gx = s_gx[t], gy = s_gy[t], gw = s_gw[t], gh = s_gh[t];
                float mx = fminf(bxx - hbw, gx - gw*0.5f);
                float Mx = fmaxf(bxx + hbw, gx + gw*0.5f);
                float my = fminf(byy - hbh, gy - gh*0.5f);
                float My = fmaxf(byy + hbh, gy + gh*0.5f);
                float cw  = bw + gw - (Mx - mx);
                float chh = bh + gh - (My - my);
                float inter = (cw > 0.f && chh > 0.f) ? cw*chh : 0.f;
                float un = pa + gw*gh - inter;
                float iou = (un > 0.f) ? inter/un : 0.f;
                maxiou = fmaxf(maxiou, iou);
                if (s_cell[t] == cell) { match = t; miou = iou; }  // last t wins
            }

            if (match >= 0) {
                float dx = x  - s_tx[match];
                float dy = y  - s_ty[match];
                float dw = p2 - s_tw[match];
                float dh = p3 - s_th[match];
                l += dx*dx + dy*dy + dw*dw + dh*dh;      // COORD_SCALE = 1
                float dc = conf - miou;
                l += 5.0f * dc*dc;                        // OBJ_SCALE = 5
            } else if (maxiou <= 0.6f) {
                l += conf*conf;                           // NOOBJ_SCALE = 1
            }
        }

        #pragma unroll
        for (int off = 32; off > 0; off >>= 1) l += __shfl_down(l, off, 64);
        if ((tid & 63) == 0) s_red[tid >> 6] = l;
        __syncthreads();
        if (tid == 0)
            ws[WS_PART + b*MBLK + bx] = s_red[0]+s_red[1]+s_red[2]+s_red[3];
    } else {
        // ---------- cls block: dedup + n_obj + class loss ----------
        const int lane = tid & 63;
        const int wv   = tid >> 6;

        // dedup (last-t-wins) + unique count, wave 0 only
        __shared__ int s_act[NT];
        __shared__ float s_nobj;
        if (tid < 64) {
            int active = 0;
            if (tid < vc) {
                active = 1;
                const int mycell = s_cell[tid];
                for (int u = tid+1; u < vc; ++u)
                    if (s_cell[u] == mycell) { active = 0; break; }
                s_act[tid] = active;
            }
            unsigned long long am = __ballot(active != 0);
            if (tid == 0) s_nobj = (float)__popcll(am);
        }
        __syncthreads();

        float csum = 0.f;
        for (int t = wv; t < vc; t += 4) {
            if (!s_act[t]) continue;
            const int cell = s_cell[t];
            const int a = cell / HW, rem = cell - a*HW;
            const float* logit = pred + ((size_t)(b*(NA*NCH) + a*NCH) + 5)*HW + rem;
            float v0 = logit[(size_t)lane*HW];
            float v1 = (lane < NC-64) ? logit[(size_t)(lane+64)*HW] : -INFINITY;
            float m = fmaxf(v0, v1);
            #pragma unroll
            for (int off = 32; off > 0; off >>= 1) m = fmaxf(m, __shfl_xor(m, off, 64));
            const int tc = s_cls[t];
            float s  = expf(v0 - m) + ((lane < NC-64) ? expf(v1 - m) : 0.f);
            float tl = ((lane == tc) ? v0 : 0.f) + ((lane + 64 == tc) ? v1 : 0.f);
            #pragma unroll
            for (int off = 32; off > 0; off >>= 1) {
                s  += __shfl_xor(s,  off, 64);
                tl += __shfl_xor(tl, off, 64);
            }
            csum += (m + logf(s)) - tl;
        }
        if (lane == 0) s_red[wv] = csum;
        __syncthreads();
        if (tid == 0) {
            ws[WS_CLSP + b] = s_red[0]+s_red[1]+s_red[2]+s_red[3];
            ws[WS_NOBJ + b] = s_nobj;
        }
    }
}

__global__ __launch_bounds__(256) void fin_k(const float* __restrict__ ws,
                                             float* __restrict__ out) {
    const int tid = threadIdx.x;
    __shared__ float s_red[4*3];
    float m = 0.f, c = 0.f, n = 0.f;
    for (int idx = tid; idx < NB*MBLK; idx += 256) m += ws[WS_PART + idx];
    if (tid < NB) { c = ws[WS_CLSP + tid]; n = ws[WS_NOBJ + tid]; }
    #pragma unroll
    for (int off = 32; off > 0; off >>= 1) {
        m += __shfl_down(m, off, 64);
        c += __shfl_down(c, off, 64);
        n += __shfl_down(n, off, 64);
    }
    const int wv = tid >> 6;
    if ((tid & 63) == 0) { s_red[wv*3] = m; s_red[wv*3+1] = c; s_red[wv*3+2] = n; }
    __syncthreads();
    if (tid == 0) {
        float M = 0.f, Cs = 0.f, Ns = 0.f;
        #pragma unroll
        for (int w = 0; w < 4; ++w) { M += s_red[w*3]; Cs += s_red[w*3+1]; Ns += s_red[w*3+2]; }
        out[0] = M + Cs / fmaxf(Ns, 1.0f);
    }
}

extern "C" void kernel_launch(void* const* d_in, const int* in_sizes, int n_in,
                              void* d_out, int out_size, void* d_ws, size_t ws_size,
                              hipStream_t stream) {
    const float* pred = (const float*)d_in[0];
    const float* tgt  = (const float*)d_in[1];
    float* ws  = (float*)d_ws;
    float* out = (float*)d_out;

    hipLaunchKernelGGL(yolo_fused, dim3(MBLK+1, NB), dim3(256), 0, stream, pred, tgt, ws);
    hipLaunchKernelGGL(fin_k, dim3(1), dim3(256), 0, stream, ws, out);
}